// Round 1
// baseline (303.006 us; speedup 1.0000x reference)
//
#include <hip/hip_runtime.h>

// ---------------------------------------------------------------------------
// PASingleRoIExtractor: RoIAlign(out=7, sn=2) on 4 FPN levels + max-combine.
// Strategy:
//   1) Transpose each level NCHW fp32 -> NHWC bf16 into d_ws (coalesced LDS
//      tile transpose). Makes the per-pixel channel vector contiguous (512B).
//   2) Main kernel: one block per roi. Per-level interp tables (premultiplied
//      uint4 offsets + weights) in LDS; each thread owns 8 channels x ~6 bins,
//      gathers corners with global_load_dwordx4, max-combines over levels,
//      stages [c][49] result tile in LDS, writes out coalesced float4.
//   3) Fallback direct-NCHW kernel if ws_size is too small (correctness net).
// ---------------------------------------------------------------------------

#define NCH 256
#define OUTS 7
#define NBIN 49

// level params (H == W, square)
__device__ __constant__ int   d_H[4]     = {256, 128, 64, 32};
__device__ __constant__ float d_scale[4] = {0.25f, 0.125f, 0.0625f, 0.03125f};
// level offsets into ws, in uint4 (16B = 8 bf16) units
__device__ __constant__ int   d_off4[4]  = {0, 2097152, 2621440, 2752512};

// interp-table entry: lo/hi offsets premultiplied to uint4-index units,
// weights as float bits.
__device__ __forceinline__ int4 make_entry(float coord, int size, int mult) {
    float valid = (coord > -1.0f && coord < (float)size) ? 1.0f : 0.0f;
    float c = fminf(fmaxf(coord, 0.0f), (float)size - 1.0f);
    int lo = (int)floorf(c);
    int hi = min(lo + 1, size - 1);
    float whi = (c - (float)lo) * valid;
    float wlo = (1.0f - (c - (float)lo)) * valid;
    int4 r;
    r.x = lo * mult;
    r.y = hi * mult;
    r.z = __float_as_int(wlo);
    r.w = __float_as_int(whi);
    return r;
}

__device__ __forceinline__ void acc8(float* acc, uint4 u, float w) {
    acc[0] = fmaf(w, __uint_as_float(u.x << 16),         acc[0]);
    acc[1] = fmaf(w, __uint_as_float(u.x & 0xffff0000u), acc[1]);
    acc[2] = fmaf(w, __uint_as_float(u.y << 16),         acc[2]);
    acc[3] = fmaf(w, __uint_as_float(u.y & 0xffff0000u), acc[3]);
    acc[4] = fmaf(w, __uint_as_float(u.z << 16),         acc[4]);
    acc[5] = fmaf(w, __uint_as_float(u.z & 0xffff0000u), acc[5]);
    acc[6] = fmaf(w, __uint_as_float(u.w << 16),         acc[6]);
    acc[7] = fmaf(w, __uint_as_float(u.w & 0xffff0000u), acc[7]);
}

__device__ __forceinline__ void do_sample(const uint4* __restrict__ base,
                                          float* acc, int4 ye, int4 xe) {
    float wyl = __int_as_float(ye.z), wyh = __int_as_float(ye.w);
    float wxl = __int_as_float(xe.z), wxh = __int_as_float(xe.w);
    uint4 ull = base[ye.x + xe.x];
    uint4 ulh = base[ye.x + xe.y];
    uint4 uhl = base[ye.y + xe.x];
    uint4 uhh = base[ye.y + xe.y];
    acc8(acc, ull, wyl * wxl);
    acc8(acc, ulh, wyl * wxh);
    acc8(acc, uhl, wyh * wxl);
    acc8(acc, uhh, wyh * wxh);
}

// ---------------------------------------------------------------------------
// NCHW fp32 -> NHWC bf16 transpose, one (y, 64x, 64c) tile per block.
// Reads coalesced along x, writes coalesced along c. LDS pad +1 kills
// bank conflicts on the transposed read.
// ---------------------------------------------------------------------------
__global__ __launch_bounds__(256) void transpose_nhwc_bf16(
    const float* __restrict__ in, unsigned short* __restrict__ out,
    int H, int W) {
    __shared__ float tile[64][65];
    int x0 = blockIdx.x * 64;
    int y  = blockIdx.y;
    int cc = blockIdx.z * 64;
    int tx = threadIdx.x & 63;
    int tq = threadIdx.x >> 6;  // 0..3
    size_t HW = (size_t)H * W;
    const float* inp = in + (size_t)cc * HW + (size_t)y * W + x0;
#pragma unroll
    for (int r = 0; r < 16; ++r) {
        int cl = tq * 16 + r;
        float v = 0.0f;
        if (x0 + tx < W) v = inp[(size_t)cl * HW + tx];
        tile[cl][tx] = v;
    }
    __syncthreads();
    int cl = threadIdx.x & 63;
#pragma unroll
    for (int r = 0; r < 16; ++r) {
        int xl = tq * 16 + r;
        int x = x0 + xl;
        if (x < W) {
            unsigned int b = __float_as_uint(tile[cl][xl]);
            b += 0x7fffu + ((b >> 16) & 1u);  // RNE to bf16
            out[((size_t)(y * W + x)) * NCH + cc + cl] = (unsigned short)(b >> 16);
        }
    }
}

// ---------------------------------------------------------------------------
// Main roi kernel: one block per roi.
// ---------------------------------------------------------------------------
__global__ __launch_bounds__(256) void roi_main(
    const uint4* __restrict__ ws, const float* __restrict__ rois,
    float* __restrict__ out) {
    __shared__ float4 smem4[NCH * NBIN / 4];   // [c][49] fp32 result tile
    __shared__ int4 tbl[4][2][14];             // [lvl][axis(y,x)][sample]
    float* smem = (float*)smem4;

    const int n = blockIdx.x;
    const int tid = threadIdx.x;
    const float* r = rois + (size_t)n * 5;

    // build interp tables: 4 lvl x 2 axes x 14 samples = 112 entries
    if (tid < 112) {
        int lvl = tid / 28;
        int e = tid % 28;
        int axis = e / 14;  // 0 = y, 1 = x
        int s = e % 14;
        int H = d_H[lvl];
        float sc = d_scale[lvl];
        float a  = (axis ? r[1] : r[2]) * sc;
        float b2 = (axis ? r[3] : r[4]) * sc;
        float binsz = fmaxf(b2 - a, 1.0f) * (1.0f / 7.0f);
        float g = (float)(s >> 1) + 0.25f + 0.5f * (float)(s & 1);
        float coord = a + g * binsz;
        int mult = axis ? 32 : H * 32;   // uint4-index units: pixel stride = 32
        tbl[lvl][axis][s] = make_entry(coord, H, mult);
    }
    __syncthreads();

    const int p = tid & 31;        // channel octet: channels 8p..8p+7
    const int h = tid >> 5;        // bin group 0..7
    const int bstart = (h * NBIN) >> 3;
    const int bend   = ((h + 1) * NBIN) >> 3;

    for (int b = bstart; b < bend; ++b) {
        int by = b / 7;
        int bx = b - by * 7;
        float m[8];
#pragma unroll
        for (int k = 0; k < 8; ++k) m[k] = -3.402823e38f;
#pragma unroll
        for (int lvl = 0; lvl < 4; ++lvl) {
            const uint4* base = ws + d_off4[lvl] + p;
            int4 ye0 = tbl[lvl][0][2 * by];
            int4 ye1 = tbl[lvl][0][2 * by + 1];
            int4 xe0 = tbl[lvl][1][2 * bx];
            int4 xe1 = tbl[lvl][1][2 * bx + 1];
            float acc[8];
#pragma unroll
            for (int k = 0; k < 8; ++k) acc[k] = 0.0f;
            do_sample(base, acc, ye0, xe0);
            do_sample(base, acc, ye0, xe1);
            do_sample(base, acc, ye1, xe0);
            do_sample(base, acc, ye1, xe1);
#pragma unroll
            for (int k = 0; k < 8; ++k) m[k] = fmaxf(m[k], acc[k] * 0.25f);
        }
#pragma unroll
        for (int k = 0; k < 8; ++k) smem[(p * 8 + k) * NBIN + b] = m[k];
    }
    __syncthreads();

    // coalesced writeout: 256*49 floats = 3136 float4
    float4* o4 = (float4*)(out + (size_t)n * (NCH * NBIN));
    for (int i = tid; i < NCH * NBIN / 4; i += 256) o4[i] = smem4[i];
}

// ---------------------------------------------------------------------------
// Fallback: direct NCHW fp32 gather (used only if ws_size is too small).
// ---------------------------------------------------------------------------
__global__ __launch_bounds__(256) void roi_direct(
    const float* __restrict__ f0, const float* __restrict__ f1,
    const float* __restrict__ f2, const float* __restrict__ f3,
    const float* __restrict__ rois, float* __restrict__ out) {
    const int n = blockIdx.x;
    const int c = threadIdx.x;
    const float* feats[4] = {f0, f1, f2, f3};
    const float* r = rois + (size_t)n * 5;
    for (int b = 0; b < NBIN; ++b) {
        int by = b / 7;
        int bx = b - by * 7;
        float m = -3.402823e38f;
#pragma unroll
        for (int lvl = 0; lvl < 4; ++lvl) {
            int H = d_H[lvl];
            float sc = d_scale[lvl];
            float x1 = r[1] * sc, y1 = r[2] * sc, x2 = r[3] * sc, y2 = r[4] * sc;
            float bw = fmaxf(x2 - x1, 1.0f) * (1.0f / 7.0f);
            float bh = fmaxf(y2 - y1, 1.0f) * (1.0f / 7.0f);
            const float* f = feats[lvl] + (size_t)c * H * H;
            float acc = 0.0f;
#pragma unroll
            for (int sy = 0; sy < 2; ++sy) {
#pragma unroll
                for (int sx = 0; sx < 2; ++sx) {
                    float yc = y1 + ((float)by + 0.25f + 0.5f * sy) * bh;
                    float xc = x1 + ((float)bx + 0.25f + 0.5f * sx) * bw;
                    int4 ey = make_entry(yc, H, H);
                    int4 ex = make_entry(xc, H, 1);
                    float wyl = __int_as_float(ey.z), wyh = __int_as_float(ey.w);
                    float wxl = __int_as_float(ex.z), wxh = __int_as_float(ex.w);
                    acc += f[ey.x + ex.x] * wyl * wxl + f[ey.x + ex.y] * wyl * wxh
                         + f[ey.y + ex.x] * wyh * wxl + f[ey.y + ex.y] * wyh * wxh;
                }
            }
            m = fmaxf(m, acc * 0.25f);
        }
        out[((size_t)n * NCH + c) * NBIN + b] = m;
    }
}

extern "C" void kernel_launch(void* const* d_in, const int* in_sizes, int n_in,
                              void* d_out, int out_size, void* d_ws, size_t ws_size,
                              hipStream_t stream) {
    const float* f0 = (const float*)d_in[0];
    const float* f1 = (const float*)d_in[1];
    const float* f2 = (const float*)d_in[2];
    const float* f3 = (const float*)d_in[3];
    const float* rois = (const float*)d_in[4];
    const int nrois = in_sizes[4] / 5;
    float* out = (float*)d_out;

    const size_t need = 44564480;  // 4 levels NHWC bf16
    if (ws_size >= need) {
        unsigned short* ws = (unsigned short*)d_ws;
        const float* fin[4] = {f0, f1, f2, f3};
        const int Hs[4] = {256, 128, 64, 32};
        const size_t offs[4] = {0, 16777216, 20971520, 22020096};  // bf16 elems
        for (int lvl = 0; lvl < 4; ++lvl) {
            int H = Hs[lvl];
            dim3 grid((H + 63) / 64, H, 4);
            transpose_nhwc_bf16<<<grid, 256, 0, stream>>>(fin[lvl], ws + offs[lvl], H, H);
        }
        roi_main<<<nrois, 256, 0, stream>>>((const uint4*)d_ws, rois, out);
    } else {
        roi_direct<<<nrois, 256, 0, stream>>>(f0, f1, f2, f3, rois, out);
    }
}

// Round 2
// 247.243 us; speedup vs baseline: 1.2255x; 1.2255x over previous
//
#include <hip/hip_runtime.h>

// ---------------------------------------------------------------------------
// PASingleRoIExtractor: RoIAlign(out=7, sn=2) on 4 FPN levels + max-combine.
//   1) transpose_fused: all 4 levels NCHW fp32 -> NHWC bf16 in ONE launch,
//      coalesced fp32 reads -> LDS tile -> uint4 (8ch) packed stores.
//   2) roi_main2: TWO blocks per roi (128 channels each) -> 26.9KB LDS,
//      6 blocks/CU, 2000 blocks. Gathers uint4 corners, max over levels,
//      stages [128][49] fp32 tile in LDS, coalesced float4 writeout.
//   3) roi_direct fallback if ws too small.
// ---------------------------------------------------------------------------

#define NCH 256
#define NBIN 49

__device__ __constant__ int   d_H[4]      = {256, 128, 64, 32};
__device__ __constant__ float d_scale[4]  = {0.25f, 0.125f, 0.0625f, 0.03125f};
__device__ __constant__ int   d_off4[4]   = {0, 2097152, 2621440, 2752512};   // uint4 units
__device__ __constant__ size_t d_offu[4]  = {0, 16777216, 20971520, 22020096}; // ushort units
__device__ __constant__ int   d_tstart[4] = {0, 4096, 5120, 5376};            // tile-block prefix
__device__ __constant__ int   d_tilesx[4] = {4, 2, 1, 1};

__device__ __forceinline__ unsigned rne_bf16(float v) {
    unsigned b = __float_as_uint(v);
    b += 0x7fffu + ((b >> 16) & 1u);
    return b >> 16;
}

__device__ __forceinline__ int4 make_entry(float coord, int size, int mult) {
    float valid = (coord > -1.0f && coord < (float)size) ? 1.0f : 0.0f;
    float c = fminf(fmaxf(coord, 0.0f), (float)size - 1.0f);
    int lo = (int)floorf(c);
    int hi = min(lo + 1, size - 1);
    float whi = (c - (float)lo) * valid;
    float wlo = (1.0f - (c - (float)lo)) * valid;
    int4 r;
    r.x = lo * mult;
    r.y = hi * mult;
    r.z = __float_as_int(wlo);
    r.w = __float_as_int(whi);
    return r;
}

__device__ __forceinline__ void acc8(float* acc, uint4 u, float w) {
    acc[0] = fmaf(w, __uint_as_float(u.x << 16),         acc[0]);
    acc[1] = fmaf(w, __uint_as_float(u.x & 0xffff0000u), acc[1]);
    acc[2] = fmaf(w, __uint_as_float(u.y << 16),         acc[2]);
    acc[3] = fmaf(w, __uint_as_float(u.y & 0xffff0000u), acc[3]);
    acc[4] = fmaf(w, __uint_as_float(u.z << 16),         acc[4]);
    acc[5] = fmaf(w, __uint_as_float(u.z & 0xffff0000u), acc[5]);
    acc[6] = fmaf(w, __uint_as_float(u.w << 16),         acc[6]);
    acc[7] = fmaf(w, __uint_as_float(u.w & 0xffff0000u), acc[7]);
}

__device__ __forceinline__ void do_sample(const uint4* __restrict__ base,
                                          float* acc, int4 ye, int4 xe) {
    float wyl = __int_as_float(ye.z), wyh = __int_as_float(ye.w);
    float wxl = __int_as_float(xe.z), wxh = __int_as_float(xe.w);
    uint4 ull = base[ye.x + xe.x];
    uint4 ulh = base[ye.x + xe.y];
    uint4 uhl = base[ye.y + xe.x];
    uint4 uhh = base[ye.y + xe.y];
    acc8(acc, ull, wyl * wxl);
    acc8(acc, ulh, wyl * wxh);
    acc8(acc, uhl, wyh * wxl);
    acc8(acc, uhh, wyh * wxh);
}

// ---------------------------------------------------------------------------
// Fused transpose: all 4 levels, NCHW fp32 -> NHWC bf16.
// Block = (64 x-pixels) x (64 channels) x 1 row. 5504 blocks total.
// Read: coalesced fp32 along x. Write: uint4 = 8 bf16 channels per lane
// (8 x 128B contiguous segments per wave instruction).
// ---------------------------------------------------------------------------
__global__ __launch_bounds__(256) void transpose_fused(
    const float* __restrict__ f0, const float* __restrict__ f1,
    const float* __restrict__ f2, const float* __restrict__ f3,
    unsigned short* __restrict__ out) {
    __shared__ float tile[64][65];

    const int bid = blockIdx.x;
    const int lvl = (bid >= d_tstart[1]) + (bid >= d_tstart[2]) + (bid >= d_tstart[3]);
    int rem = bid - d_tstart[lvl];
    const int H = d_H[lvl];
    const int tnx = d_tilesx[lvl];
    const int xt = rem % tnx; rem /= tnx;
    const int y  = rem % H;
    const int cg = rem / H;              // channel group of 64
    const int W = H;
    const int x0 = xt * 64;
    const float* in = (lvl == 0) ? f0 : (lvl == 1) ? f1 : (lvl == 2) ? f2 : f3;
    unsigned short* o = out + d_offu[lvl];

    const int tid = threadIdx.x;
    const int tx = tid & 63;
    const int tq = tid >> 6;
    const size_t HW = (size_t)H * W;
    const float* inp = in + (size_t)(cg * 64) * HW + (size_t)y * W + x0;
    const bool xin = (x0 + tx) < W;
#pragma unroll
    for (int r = 0; r < 16; ++r) {
        int cl = tq * 16 + r;
        tile[cl][tx] = xin ? inp[(size_t)cl * HW + tx] : 0.0f;
    }
    __syncthreads();

    const int o8 = tid & 7;   // channel octet within the 64-ch group
    const int xi = tid >> 3;  // 0..31
#pragma unroll
    for (int pass = 0; pass < 2; ++pass) {
        int px = xi + pass * 32;
        int x = x0 + px;
        if (x < W) {
            unsigned w0, w1, w2, w3;
            w0 = rne_bf16(tile[o8 * 8 + 0][px]) | (rne_bf16(tile[o8 * 8 + 1][px]) << 16);
            w1 = rne_bf16(tile[o8 * 8 + 2][px]) | (rne_bf16(tile[o8 * 8 + 3][px]) << 16);
            w2 = rne_bf16(tile[o8 * 8 + 4][px]) | (rne_bf16(tile[o8 * 8 + 5][px]) << 16);
            w3 = rne_bf16(tile[o8 * 8 + 6][px]) | (rne_bf16(tile[o8 * 8 + 7][px]) << 16);
            uint4* dst = (uint4*)(o + (size_t)(y * W + x) * NCH + cg * 64 + o8 * 8);
            *dst = make_uint4(w0, w1, w2, w3);
        }
    }
}

// ---------------------------------------------------------------------------
// Main roi kernel: TWO blocks per roi, each handles 128 channels.
// ---------------------------------------------------------------------------
__global__ __launch_bounds__(256) void roi_main2(
    const uint4* __restrict__ ws, const float* __restrict__ rois,
    float* __restrict__ out) {
    __shared__ float4 smem4[128 * NBIN / 4];   // 25088 B: [128 ch][49 bins] fp32
    __shared__ int4 tbl[4][2][14];             // [lvl][axis(y,x)][sample]
    float* smem = (float*)smem4;

    const int n    = blockIdx.x >> 1;
    const int half = blockIdx.x & 1;
    const int tid  = threadIdx.x;
    const float* r = rois + (size_t)n * 5;

    if (tid < 112) {
        int lvl = tid / 28;
        int e = tid % 28;
        int axis = e / 14;  // 0 = y, 1 = x
        int s = e % 14;
        int H = d_H[lvl];
        float sc = d_scale[lvl];
        float a  = (axis ? r[1] : r[2]) * sc;
        float b2 = (axis ? r[3] : r[4]) * sc;
        float binsz = fmaxf(b2 - a, 1.0f) * (1.0f / 7.0f);
        float g = (float)(s >> 1) + 0.25f + 0.5f * (float)(s & 1);
        float coord = a + g * binsz;
        int mult = axis ? 32 : H * 32;   // uint4-index units: pixel = 32 uint4
        tbl[lvl][axis][s] = make_entry(coord, H, mult);
    }
    __syncthreads();

    const int p = tid & 15;            // octet within this block's 128 channels
    const int h = tid >> 4;            // bin group 0..15
    const int octet = half * 16 + p;   // global octet 0..31
    const int bstart = (h * NBIN) >> 4;
    const int bend   = ((h + 1) * NBIN) >> 4;

    for (int b = bstart; b < bend; ++b) {
        int by = b / 7;
        int bx = b - by * 7;
        float m[8];
#pragma unroll
        for (int k = 0; k < 8; ++k) m[k] = -3.402823e38f;
#pragma unroll
        for (int lvl = 0; lvl < 4; ++lvl) {
            const uint4* base = ws + d_off4[lvl] + octet;
            int4 ye0 = tbl[lvl][0][2 * by];
            int4 ye1 = tbl[lvl][0][2 * by + 1];
            int4 xe0 = tbl[lvl][1][2 * bx];
            int4 xe1 = tbl[lvl][1][2 * bx + 1];
            float acc[8];
#pragma unroll
            for (int k = 0; k < 8; ++k) acc[k] = 0.0f;
            do_sample(base, acc, ye0, xe0);
            do_sample(base, acc, ye0, xe1);
            do_sample(base, acc, ye1, xe0);
            do_sample(base, acc, ye1, xe1);
#pragma unroll
            for (int k = 0; k < 8; ++k) m[k] = fmaxf(m[k], acc[k] * 0.25f);
        }
#pragma unroll
        for (int k = 0; k < 8; ++k) smem[(p * 8 + k) * NBIN + b] = m[k];
    }
    __syncthreads();

    // coalesced writeout: this block's 128*49 floats = 1568 float4
    float4* o4 = (float4*)(out + (size_t)n * (NCH * NBIN) + (size_t)half * (128 * NBIN));
    for (int i = tid; i < 128 * NBIN / 4; i += 256) o4[i] = smem4[i];
}

// ---------------------------------------------------------------------------
// Fallback: direct NCHW fp32 gather (used only if ws_size is too small).
// ---------------------------------------------------------------------------
__global__ __launch_bounds__(256) void roi_direct(
    const float* __restrict__ f0, const float* __restrict__ f1,
    const float* __restrict__ f2, const float* __restrict__ f3,
    const float* __restrict__ rois, float* __restrict__ out) {
    const int n = blockIdx.x;
    const int c = threadIdx.x;
    const float* feats[4] = {f0, f1, f2, f3};
    const float* r = rois + (size_t)n * 5;
    for (int b = 0; b < NBIN; ++b) {
        int by = b / 7;
        int bx = b - by * 7;
        float m = -3.402823e38f;
#pragma unroll
        for (int lvl = 0; lvl < 4; ++lvl) {
            int H = d_H[lvl];
            float sc = d_scale[lvl];
            float x1 = r[1] * sc, y1 = r[2] * sc, x2 = r[3] * sc, y2 = r[4] * sc;
            float bw = fmaxf(x2 - x1, 1.0f) * (1.0f / 7.0f);
            float bh = fmaxf(y2 - y1, 1.0f) * (1.0f / 7.0f);
            const float* f = feats[lvl] + (size_t)c * H * H;
            float acc = 0.0f;
#pragma unroll
            for (int sy = 0; sy < 2; ++sy) {
#pragma unroll
                for (int sx = 0; sx < 2; ++sx) {
                    float yc = y1 + ((float)by + 0.25f + 0.5f * sy) * bh;
                    float xc = x1 + ((float)bx + 0.25f + 0.5f * sx) * bw;
                    int4 ey = make_entry(yc, H, H);
                    int4 ex = make_entry(xc, H, 1);
                    float wyl = __int_as_float(ey.z), wyh = __int_as_float(ey.w);
                    float wxl = __int_as_float(ex.z), wxh = __int_as_float(ex.w);
                    acc += f[ey.x + ex.x] * wyl * wxl + f[ey.x + ex.y] * wyl * wxh
                         + f[ey.y + ex.x] * wyh * wxl + f[ey.y + ex.y] * wyh * wxh;
                }
            }
            m = fmaxf(m, acc * 0.25f);
        }
        out[((size_t)n * NCH + c) * NBIN + b] = m;
    }
}

extern "C" void kernel_launch(void* const* d_in, const int* in_sizes, int n_in,
                              void* d_out, int out_size, void* d_ws, size_t ws_size,
                              hipStream_t stream) {
    const float* f0 = (const float*)d_in[0];
    const float* f1 = (const float*)d_in[1];
    const float* f2 = (const float*)d_in[2];
    const float* f3 = (const float*)d_in[3];
    const float* rois = (const float*)d_in[4];
    const int nrois = in_sizes[4] / 5;
    float* out = (float*)d_out;

    const size_t need = 44564480;  // 4 levels NHWC bf16
    if (ws_size >= need) {
        unsigned short* ws = (unsigned short*)d_ws;
        transpose_fused<<<5504, 256, 0, stream>>>(f0, f1, f2, f3, ws);
        roi_main2<<<2 * nrois, 256, 0, stream>>>((const uint4*)d_ws, rois, out);
    } else {
        roi_direct<<<nrois, 256, 0, stream>>>(f0, f1, f2, f3, rois, out);
    }
}

// Round 3
// 217.015 us; speedup vs baseline: 1.3962x; 1.1393x over previous
//
#include <hip/hip_runtime.h>

// ---------------------------------------------------------------------------
// PASingleRoIExtractor: RoIAlign(out=7, sn=2) on 4 FPN levels + max-combine.
//   1) transpose_fused: 4 levels NCHW fp32 -> NHWC **fp16** in one launch.
//      float2 coalesced reads -> LDS -> cvt_pkrtz f16 pairs -> uint4 stores.
//   2) roi_main4: FOUR blocks/roi (64 ch each, 14.3KB LDS -> 8 blocks/CU).
//      Inner loop = v_perm corner-pair pack + v_dot2_f32_f16 with
//      v_pk_mul_f16 weight pairs (guarded by __has_builtin, scalar fallback).
//   3) roi_direct fallback if ws too small.
// ---------------------------------------------------------------------------

#define NCH 256
#define NBIN 49

typedef _Float16 half2v __attribute__((ext_vector_type(2)));

#if defined(__has_builtin)
#if __has_builtin(__builtin_amdgcn_fdot2)
#define HAVE_FDOT2 1
#endif
#if __has_builtin(__builtin_amdgcn_cvt_pkrtz)
#define HAVE_PKRTZ 1
#endif
#endif

__device__ __constant__ int    d_H[4]      = {256, 128, 64, 32};
__device__ __constant__ float  d_scale[4]  = {0.25f, 0.125f, 0.0625f, 0.03125f};
__device__ __constant__ int    d_off4[4]   = {0, 2097152, 2621440, 2752512};    // uint4 units
__device__ __constant__ size_t d_offu[4]   = {0, 16777216, 20971520, 22020096}; // f16 units
__device__ __constant__ int    d_tstart[4] = {0, 4096, 5120, 5376};
__device__ __constant__ int    d_tilesx[4] = {4, 2, 1, 1};

__device__ __forceinline__ int pack_h2(float a, float b) {
#ifdef HAVE_PKRTZ
    return __builtin_bit_cast(int, __builtin_amdgcn_cvt_pkrtz(a, b));
#else
    half2v h;
    h.x = (_Float16)a;
    h.y = (_Float16)b;
    return __builtin_bit_cast(int, h);
#endif
}
__device__ __forceinline__ half2v bc_h2(int x) { return __builtin_bit_cast(half2v, x); }
__device__ __forceinline__ half2v bc_h2u(unsigned x) { return __builtin_bit_cast(half2v, x); }

// dot of {cornerA_ch, cornerB_ch} f16 pair with weight pair, fp32 accumulate.
// v_perm: S1 (2nd operand) supplies result bytes 0..3 -> uLL goes to low half,
// matching the low weight lane (wy*wx_lo).
#ifdef HAVE_FDOT2
#define ACC2(uLLc, uLHc, w2, k0)                                                                       \
    acc[k0] = __builtin_amdgcn_fdot2(bc_h2u(__builtin_amdgcn_perm((uLHc), (uLLc), 0x05040100u)), (w2), \
                                     acc[k0], false);                                                  \
    acc[k0 + 1] = __builtin_amdgcn_fdot2(                                                              \
        bc_h2u(__builtin_amdgcn_perm((uLHc), (uLLc), 0x07060302u)), (w2), acc[k0 + 1], false)
#else
#define ACC2(uLLc, uLHc, w2, k0)                                       \
    do {                                                               \
        half2v a_ = bc_h2u(uLLc), b_ = bc_h2u(uLHc);                   \
        float w0_ = (float)(w2).x, w1_ = (float)(w2).y;                \
        acc[k0]     = fmaf((float)a_.x, w0_, acc[k0]);                 \
        acc[k0]     = fmaf((float)b_.x, w1_, acc[k0]);                 \
        acc[k0 + 1] = fmaf((float)a_.y, w0_, acc[k0 + 1]);             \
        acc[k0 + 1] = fmaf((float)b_.y, w1_, acc[k0 + 1]);             \
    } while (0)
#endif

// ye: {ylo_off, yhi_off, h2{wyl,wyl}, h2{wyh,wyh}}  xe: {xlo_off, xhi_off, h2{wxl,wxh}, 0}
__device__ __forceinline__ void do_sample(const uint4* __restrict__ base, float* acc, int4 ye,
                                          int4 xe) {
    uint4 uLL = base[ye.x + xe.x];
    uint4 uLH = base[ye.x + xe.y];
    uint4 uHL = base[ye.y + xe.x];
    uint4 uHH = base[ye.y + xe.y];
    half2v wx = bc_h2(xe.z);
    half2v wlo = bc_h2(ye.z) * wx;  // {wyl*wxl, wyl*wxh}  (v_pk_mul_f16)
    half2v whi = bc_h2(ye.w) * wx;  // {wyh*wxl, wyh*wxh}
    ACC2(uLL.x, uLH.x, wlo, 0);
    ACC2(uLL.y, uLH.y, wlo, 2);
    ACC2(uLL.z, uLH.z, wlo, 4);
    ACC2(uLL.w, uLH.w, wlo, 6);
    ACC2(uHL.x, uHH.x, whi, 0);
    ACC2(uHL.y, uHH.y, whi, 2);
    ACC2(uHL.z, uHH.z, whi, 4);
    ACC2(uHL.w, uHH.w, whi, 6);
}

// ---------------------------------------------------------------------------
// Fused transpose: NCHW fp32 -> NHWC f16, all 4 levels, 5504 blocks.
// Read: float2/lane coalesced along x (2 x 256B per wave inst).
// LDS: stride-66 float rows (8B-aligned b64 writes, 2-way banks).
// Write: cvt_pkrtz pairs -> uint4 (8 ch = 16B/lane).
// ---------------------------------------------------------------------------
__global__ __launch_bounds__(256) void transpose_fused(
    const float* __restrict__ f0, const float* __restrict__ f1, const float* __restrict__ f2,
    const float* __restrict__ f3, unsigned short* __restrict__ out) {
    __shared__ float tile[64 * 66];

    const int bid = blockIdx.x;
    const int lvl = (bid >= d_tstart[1]) + (bid >= d_tstart[2]) + (bid >= d_tstart[3]);
    int rem = bid - d_tstart[lvl];
    const int H = d_H[lvl];
    const int tnx = d_tilesx[lvl];
    const int xt = rem % tnx;
    rem /= tnx;
    const int y = rem % H;
    const int cg = rem / H;  // channel group of 64
    const int x0 = xt * 64;
    const float* in = (lvl == 0) ? f0 : (lvl == 1) ? f1 : (lvl == 2) ? f2 : f3;
    unsigned short* o = out + d_offu[lvl];

    const int tid = threadIdx.x;
    const int tx2 = tid & 31;  // float2 column
    const int wv = tid >> 5;   // 0..7
    const size_t HW = (size_t)H * H;
    const float* inp = in + (size_t)(cg * 64) * HW + (size_t)y * H + x0;
    const bool xin = (x0 + tx2 * 2) < H;
#pragma unroll
    for (int r = 0; r < 8; ++r) {
        int cl = wv * 8 + r;
        float2 v = make_float2(0.0f, 0.0f);
        if (xin) v = *(const float2*)(inp + (size_t)cl * HW + tx2 * 2);
        *(float2*)&tile[cl * 66 + tx2 * 2] = v;
    }
    __syncthreads();

    const int o8 = tid & 7;   // channel octet in the 64-ch group
    const int xi = tid >> 3;  // 0..31
#pragma unroll
    for (int pass = 0; pass < 2; ++pass) {
        int px = xi + pass * 32;
        int x = x0 + px;
        if (x < H) {
            const float* col = &tile[o8 * 8 * 66 + px];
            unsigned d0 = (unsigned)pack_h2(col[0 * 66], col[1 * 66]);
            unsigned d1 = (unsigned)pack_h2(col[2 * 66], col[3 * 66]);
            unsigned d2 = (unsigned)pack_h2(col[4 * 66], col[5 * 66]);
            unsigned d3 = (unsigned)pack_h2(col[6 * 66], col[7 * 66]);
            uint4* dst = (uint4*)(o + (size_t)(y * H + x) * NCH + cg * 64 + o8 * 8);
            *dst = make_uint4(d0, d1, d2, d3);
        }
    }
}

// ---------------------------------------------------------------------------
// Main roi kernel: FOUR blocks per roi, 64 channels each.
// ---------------------------------------------------------------------------
__global__ __launch_bounds__(256) void roi_main4(const uint4* __restrict__ ws,
                                                 const float* __restrict__ rois,
                                                 float* __restrict__ out) {
    __shared__ float smem[64 * NBIN];  // 12544 B
    __shared__ int4 tbl[4][2][14];     // 1792 B

    const int n = blockIdx.x >> 2;
    const int quarter = blockIdx.x & 3;
    const int tid = threadIdx.x;
    const float* r = rois + (size_t)n * 5;

    if (tid < 112) {
        int lvl = tid / 28;
        int e = tid % 28;
        int axis = e / 14;  // 0 = y, 1 = x
        int s = e % 14;
        int H = d_H[lvl];
        float sc = d_scale[lvl];
        float a = (axis ? r[1] : r[2]) * sc;
        float b2 = (axis ? r[3] : r[4]) * sc;
        float binsz = fmaxf(b2 - a, 1.0f) * (1.0f / 7.0f);
        float g = (float)(s >> 1) + 0.25f + 0.5f * (float)(s & 1);
        float coord = a + g * binsz;
        float valid = (coord > -1.0f && coord < (float)H) ? 1.0f : 0.0f;
        float c = fminf(fmaxf(coord, 0.0f), (float)H - 1.0f);
        int lo = (int)floorf(c);
        int hi = min(lo + 1, H - 1);
        float whi = (c - (float)lo) * valid;
        float wlo = (1.0f - (c - (float)lo)) * valid;
        int mult = axis ? 32 : H * 32;  // uint4 units: pixel = 32 uint4
        int4 t;
        t.x = lo * mult;
        t.y = hi * mult;
        if (axis) {
            t.z = pack_h2(wlo, whi);
            t.w = 0;
        } else {
            t.z = pack_h2(wlo, wlo);
            t.w = pack_h2(whi, whi);
        }
        tbl[lvl][axis][s] = t;
    }
    __syncthreads();

    const int p = tid & 7;            // octet within this block's 64 channels
    const int h = tid >> 3;           // 0..31 bin group
    const int octet = quarter * 8 + p;
    const int bstart = (h * NBIN) >> 5;
    const int bend = ((h + 1) * NBIN) >> 5;

    for (int b = bstart; b < bend; ++b) {
        int by = b / 7;
        int bx = b - by * 7;
        float m[8];
#pragma unroll
        for (int k = 0; k < 8; ++k) m[k] = -3.402823e38f;
#pragma unroll
        for (int lvl = 0; lvl < 4; ++lvl) {
            const uint4* base = ws + d_off4[lvl] + octet;
            int4 ye0 = tbl[lvl][0][2 * by];
            int4 ye1 = tbl[lvl][0][2 * by + 1];
            int4 xe0 = tbl[lvl][1][2 * bx];
            int4 xe1 = tbl[lvl][1][2 * bx + 1];
            float acc[8];
#pragma unroll
            for (int k = 0; k < 8; ++k) acc[k] = 0.0f;
            do_sample(base, acc, ye0, xe0);
            do_sample(base, acc, ye0, xe1);
            do_sample(base, acc, ye1, xe0);
            do_sample(base, acc, ye1, xe1);
#pragma unroll
            for (int k = 0; k < 8; ++k) m[k] = fmaxf(m[k], acc[k] * 0.25f);
        }
#pragma unroll
        for (int k = 0; k < 8; ++k) smem[(p * 8 + k) * NBIN + b] = m[k];
    }
    __syncthreads();

    float4* o4 = (float4*)(out + (size_t)n * (NCH * NBIN) + (size_t)quarter * (64 * NBIN));
    const float4* s4 = (const float4*)smem;
    for (int i = tid; i < 64 * NBIN / 4; i += 256) o4[i] = s4[i];
}

// ---------------------------------------------------------------------------
// Fallback: direct NCHW fp32 gather (only if ws too small).
// ---------------------------------------------------------------------------
__device__ __forceinline__ int4 make_entry_f(float coord, int size, int mult) {
    float valid = (coord > -1.0f && coord < (float)size) ? 1.0f : 0.0f;
    float c = fminf(fmaxf(coord, 0.0f), (float)size - 1.0f);
    int lo = (int)floorf(c);
    int hi = min(lo + 1, size - 1);
    float whi = (c - (float)lo) * valid;
    float wlo = (1.0f - (c - (float)lo)) * valid;
    int4 r;
    r.x = lo * mult;
    r.y = hi * mult;
    r.z = __float_as_int(wlo);
    r.w = __float_as_int(whi);
    return r;
}

__global__ __launch_bounds__(256) void roi_direct(
    const float* __restrict__ f0, const float* __restrict__ f1, const float* __restrict__ f2,
    const float* __restrict__ f3, const float* __restrict__ rois, float* __restrict__ out) {
    const int n = blockIdx.x;
    const int c = threadIdx.x;
    const float* feats[4] = {f0, f1, f2, f3};
    const float* r = rois + (size_t)n * 5;
    for (int b = 0; b < NBIN; ++b) {
        int by = b / 7;
        int bx = b - by * 7;
        float m = -3.402823e38f;
#pragma unroll
        for (int lvl = 0; lvl < 4; ++lvl) {
            int H = d_H[lvl];
            float sc = d_scale[lvl];
            float x1 = r[1] * sc, y1 = r[2] * sc, x2 = r[3] * sc, y2 = r[4] * sc;
            float bw = fmaxf(x2 - x1, 1.0f) * (1.0f / 7.0f);
            float bh = fmaxf(y2 - y1, 1.0f) * (1.0f / 7.0f);
            const float* f = feats[lvl] + (size_t)c * H * H;
            float acc = 0.0f;
#pragma unroll
            for (int sy = 0; sy < 2; ++sy) {
#pragma unroll
                for (int sx = 0; sx < 2; ++sx) {
                    float yc = y1 + ((float)by + 0.25f + 0.5f * sy) * bh;
                    float xc = x1 + ((float)bx + 0.25f + 0.5f * sx) * bw;
                    int4 ey = make_entry_f(yc, H, H);
                    int4 ex = make_entry_f(xc, H, 1);
                    float wyl = __int_as_float(ey.z), wyh = __int_as_float(ey.w);
                    float wxl = __int_as_float(ex.z), wxh = __int_as_float(ex.w);
                    acc += f[ey.x + ex.x] * wyl * wxl + f[ey.x + ex.y] * wyl * wxh +
                           f[ey.y + ex.x] * wyh * wxl + f[ey.y + ex.y] * wyh * wxh;
                }
            }
            m = fmaxf(m, acc * 0.25f);
        }
        out[((size_t)n * NCH + c) * NBIN + b] = m;
    }
}

extern "C" void kernel_launch(void* const* d_in, const int* in_sizes, int n_in, void* d_out,
                              int out_size, void* d_ws, size_t ws_size, hipStream_t stream) {
    const float* f0 = (const float*)d_in[0];
    const float* f1 = (const float*)d_in[1];
    const float* f2 = (const float*)d_in[2];
    const float* f3 = (const float*)d_in[3];
    const float* rois = (const float*)d_in[4];
    const int nrois = in_sizes[4] / 5;
    float* out = (float*)d_out;

    const size_t need = 44564480;  // 4 levels NHWC f16
    if (ws_size >= need) {
        unsigned short* ws = (unsigned short*)d_ws;
        transpose_fused<<<5504, 256, 0, stream>>>(f0, f1, f2, f3, ws);
        roi_main4<<<4 * nrois, 256, 0, stream>>>((const uint4*)d_ws, rois, out);
    } else {
        roi_direct<<<nrois, 256, 0, stream>>>(f0, f1, f2, f3, rois, out);
    }
}